// Round 3
// baseline (1220.510 us; speedup 1.0000x reference)
//
#include <hip/hip_runtime.h>
#include <math.h>

// Poincare fully-connected (hypll / Shimizu et al.), c = 1.
// B=1048576, IN=64, OUT=64, all fp32.
//
// R3 design: block = 256 threads = 64 rows. lane = row; wave w owns outputs
// o in [16w, 16w+16). zT + per-o constants staged in LDS (wave-uniform
// ds_read_b128 broadcasts in the dot loop). w kept in 16 VGPRs per lane;
// sum(w^2) cross-wave via LDS partials; scaled w goes through a padded
// [64][65] LDS tile -> 4 coalesced float4 store rounds.
// LDS ~35 KB -> 4 blocks/CU = 16 waves/CU; VGPR ~104 (<=128 via launch_bounds).

__global__ void hl_prep(const float* __restrict__ z, const float* __restrict__ bias,
                        float* __restrict__ ws) {
    const int o = threadIdx.x;  // 0..63
    float n2 = 0.f;
    #pragma unroll 8
    for (int k = 0; k < 64; ++k) {
        float v = z[k * 64 + o];
        ws[o * 64 + k] = v;            // zT[o][k]
        n2 = fmaf(v, v, n2);
    }
    const float zn = fmaxf(sqrtf(n2), 1e-15f);
    const float t = 2.f * bias[o];     // 2*sqrt(c)*bias, c=1
    const float e = expf(t);
    const float ei = 1.f / e;
    float4 c;
    c.x = 0.5f * (e + ei) / zn;        // K1 = cosh(2b)/zn
    c.y = 0.5f * (e - ei);             // K2 = sinh(2b)
    c.z = 2.f * zn;                    // K4 = 2*zn
    c.w = 0.f;
    reinterpret_cast<float4*>(ws + 4096)[o] = c;
}

template <bool WS>
__global__ __launch_bounds__(256, 4)
void hl_main(const float* __restrict__ x, const float* __restrict__ z,
             const float* __restrict__ bias, const float* __restrict__ ws,
             float* __restrict__ out) {
    __shared__ float  zt[4096];        // zT[o][k], uniform reads (broadcast)
    __shared__ float4 kc[64];          // per-o constants
    __shared__ float  wt[64 * 65];     // padded w tile (2-way = free)
    __shared__ float  pp[4 * 64];      // sw2 partials [wave][row]

    const int tid  = threadIdx.x;
    const int wave = tid >> 6;
    const int lane = tid & 63;         // = row within tile

    // ---- issue own x row loads early (64 floats -> 16 float4) ----
    const long row0 = (long)blockIdx.x * 64;
    const float* __restrict__ xrow = x + (row0 + lane) * 64;
    float xs[64];
    #pragma unroll
    for (int i = 0; i < 16; ++i) {
        float4 f = reinterpret_cast<const float4*>(xrow)[i];
        xs[4*i+0] = f.x; xs[4*i+1] = f.y; xs[4*i+2] = f.z; xs[4*i+3] = f.w;
    }

    // ---- stage zT + consts into LDS ----
    if (WS) {
        const float4* __restrict__ s4 = reinterpret_cast<const float4*>(ws);
        float4* zt4 = reinterpret_cast<float4*>(zt);
        #pragma unroll
        for (int t = 0; t < 4; ++t) zt4[t * 256 + tid] = s4[t * 256 + tid];
        if (tid < 64) kc[tid] = reinterpret_cast<const float4*>(ws + 4096)[tid];
    } else {
        if (tid < 64) {
            const int o = tid;
            float n2 = 0.f;
            for (int k = 0; k < 64; ++k) {
                float v = z[k * 64 + o];
                zt[o * 64 + k] = v;
                n2 = fmaf(v, v, n2);
            }
            const float zn = fmaxf(__builtin_amdgcn_sqrtf(n2), 1e-15f);
            const float e  = __builtin_amdgcn_exp2f(2.f * bias[o] * 1.4426950408889634f);
            const float ei = __builtin_amdgcn_rcpf(e);
            float4 c;
            c.x = 0.5f * (e + ei) * __builtin_amdgcn_rcpf(zn);
            c.y = 0.5f * (e - ei);
            c.z = 2.f * zn;
            c.w = 0.f;
            kc[o] = c;
        }
    }

    // ---- ||x||^2, lambda (in-lane) ----
    float n0 = 0.f, n1 = 0.f, n2 = 0.f, n3 = 0.f;
    #pragma unroll
    for (int j = 0; j < 16; ++j) {
        n0 = fmaf(xs[4*j+0], xs[4*j+0], n0);
        n1 = fmaf(xs[4*j+1], xs[4*j+1], n1);
        n2 = fmaf(xs[4*j+2], xs[4*j+2], n2);
        n3 = fmaf(xs[4*j+3], xs[4*j+3], n3);
    }
    const float nx2 = (n0 + n1) + (n2 + n3);
    const float lam = 2.f * __builtin_amdgcn_rcpf(1.f - nx2);   // ||x|| <= 0.9

    __syncthreads();

    // ---- 16 outputs per lane, w kept in registers ----
    const int obase = wave * 16;
    float wv[16];
    float sw2 = 0.f;
    #pragma unroll 4
    for (int j = 0; j < 16; ++j) {
        const int o = obase + j;
        const float4* __restrict__ zp = reinterpret_cast<const float4*>(zt + o * 64);
        float a0 = 0.f, a1 = 0.f, a2 = 0.f, a3 = 0.f;
        #pragma unroll
        for (int q = 0; q < 16; ++q) {
            float4 zv = zp[q];                     // wave-uniform broadcast
            a0 = fmaf(xs[4*q+0], zv.x, a0);
            a1 = fmaf(xs[4*q+1], zv.y, a1);
            a2 = fmaf(xs[4*q+2], zv.z, a2);
            a3 = fmaf(xs[4*q+3], zv.w, a3);
        }
        const float4 c = kc[o];
        const float xz = (a0 + a1) + (a2 + a3);
        // u = lam*(xz*K1 - K2) + K2
        const float u  = fmaf(lam, fmaf(xz, c.x, -c.y), c.y);
        const float au = fabsf(u);
        // asinh/sinh fused: t = |u|+sqrt(u^2+1); e^|v| = exp2(K4*log2(t))
        const float sq = __builtin_amdgcn_sqrtf(fmaf(au, au, 1.f));
        const float lg = __builtin_amdgcn_logf(au + sq);      // log2
        const float e  = __builtin_amdgcn_exp2f(c.z * lg);    // 2^x
        const float ei = __builtin_amdgcn_rcpf(e);
        float w = fmaf(0.5f, e, -0.5f * ei);                  // sinh(|v|)
        w = copysignf(w, u);
        wv[j] = w;
        sw2 = fmaf(w, w, sw2);
    }

    // ---- cross-wave sum(w^2) per row ----
    pp[wave * 64 + lane] = sw2;
    __syncthreads();
    const float tot = (pp[lane] + pp[64 + lane]) + (pp[128 + lane] + pp[192 + lane]);
    const float scale = __builtin_amdgcn_rcpf(1.f + __builtin_amdgcn_sqrtf(1.f + tot));

    // ---- scaled w -> padded LDS tile ----
    #pragma unroll
    for (int j = 0; j < 16; ++j) wt[lane * 65 + obase + j] = wv[j] * scale;
    __syncthreads();

    // ---- coalesced float4 stores ----
    float4* __restrict__ orow = reinterpret_cast<float4*>(out + row0 * 64);
    #pragma unroll
    for (int t = 0; t < 4; ++t) {
        const int idx = t * 256 + tid;       // float4 index in 64x64 tile
        const int i   = idx >> 4;            // row
        const int o4  = idx & 15;
        const float* __restrict__ p = wt + i * 65 + o4 * 4;
        float4 v;
        v.x = p[0]; v.y = p[1]; v.z = p[2]; v.w = p[3];
        orow[idx] = v;
    }
}

extern "C" void kernel_launch(void* const* d_in, const int* in_sizes, int n_in,
                              void* d_out, int out_size, void* d_ws, size_t ws_size,
                              hipStream_t stream) {
    const float* x    = (const float*)d_in[0];
    const float* z    = (const float*)d_in[1];
    const float* bias = (const float*)d_in[2];
    float* out = (float*)d_out;
    float* ws  = (float*)d_ws;

    const long rows   = (long)in_sizes[0] / 64;   // 1048576
    const int  blocks = (int)(rows / 64);         // 64 rows per block

    if (ws_size >= (size_t)(4096 + 256) * sizeof(float)) {
        hl_prep<<<1, 64, 0, stream>>>(z, bias, ws);
        hl_main<true><<<blocks, 256, 0, stream>>>(x, z, bias, ws, out);
    } else {
        hl_main<false><<<blocks, 256, 0, stream>>>(x, z, bias, nullptr, out);
    }
}